// Round 1
// baseline (293.981 us; speedup 1.0000x reference)
//
#include <hip/hip_runtime.h>
#include <hip/hip_bf16.h>

#define HWsz 16384
#define Cdim 64
#define HIDd 128
#define NEXP 4
#define NBAT 16

typedef _Float16 h8 __attribute__((ext_vector_type(8)));
typedef _Float16 h4 __attribute__((ext_vector_type(4)));
typedef float f4 __attribute__((ext_vector_type(4)));

// d_ws layout (bytes)
#define OFF_W1F 0        // 4*128*64 f16   = 65536 B
#define OFF_W2F 65536    // 4*128*128 f16  = 131072 B
#define OFF_W3F 196608   // 4*64*128 f16   = 65536 B
#define OFF_B1F 262144   // 4*128 f32      = 2048 B
#define OFF_B2F 264192   // 4*128 f32      = 2048 B
#define OFF_B3F 266240   // 4*64 f32       = 1024 B
#define OFF_GAP 267264   // 16*64 f32      = 4096 B
#define OFF_GIDX 271360  // 16*2 int       = 128 B
#define OFF_GW  271488   // 16*2 f32       = 128 B

// ---------------- BN fold + f16 cast ----------------
__global__ void fold_k(const float* __restrict__ W1, const float* __restrict__ b1,
                       const float* __restrict__ g1, const float* __restrict__ be1,
                       const float* __restrict__ m1, const float* __restrict__ v1,
                       const float* __restrict__ W2, const float* __restrict__ b2,
                       const float* __restrict__ g2, const float* __restrict__ be2,
                       const float* __restrict__ m2, const float* __restrict__ v2,
                       const float* __restrict__ W3, const float* __restrict__ b3,
                       _Float16* __restrict__ W1f, _Float16* __restrict__ W2f,
                       _Float16* __restrict__ W3f,
                       float* __restrict__ b1f, float* __restrict__ b2f,
                       float* __restrict__ b3f)
{
  const int i = blockIdx.x * 256 + threadIdx.x;
  if (i < 32768) {                       // W1 [e][o][c], eo = i/64
    const int eo = i >> 6;
    const float inv = g1[eo] * rsqrtf(v1[eo] + 1e-5f);
    W1f[i] = (_Float16)(W1[i] * inv);
  } else if (i < 98304) {                // W2 [e][o][i], eo = j/128
    const int j = i - 32768;
    const int eo = j >> 7;
    const float inv = g2[eo] * rsqrtf(v2[eo] + 1e-5f);
    W2f[j] = (_Float16)(W2[j] * inv);
  } else if (i < 131072) {               // W3 (no BN)
    const int k = i - 98304;
    W3f[k] = (_Float16)W3[k];
  } else if (i < 131584) {               // b1'
    const int l = i - 131072;
    const float inv = g1[l] * rsqrtf(v1[l] + 1e-5f);
    b1f[l] = b1[l] * inv + be1[l] - m1[l] * inv;
  } else if (i < 132096) {               // b2'
    const int l = i - 131584;
    const float inv = g2[l] * rsqrtf(v2[l] + 1e-5f);
    b2f[l] = b2[l] * inv + be2[l] - m2[l] * inv;
  } else if (i < 132352) {               // b3'
    b3f[i - 132096] = b3[i - 132096];
  }
}

// ---------------- global average pool ----------------
__global__ void gap_k(const float* __restrict__ x, float* __restrict__ gap)
{
  const int bc = blockIdx.x;             // b*64 + c, 1024 blocks
  const float* p = x + (size_t)bc * HWsz;
  const int t = threadIdx.x;             // 256
  float s = 0.f;
  for (int i = t; i < HWsz / 4; i += 256) {
    const float4 v = ((const float4*)p)[i];
    s += v.x + v.y + v.z + v.w;
  }
  for (int off = 32; off; off >>= 1) s += __shfl_down(s, off, 64);
  __shared__ float red[4];
  if ((t & 63) == 0) red[t >> 6] = s;
  __syncthreads();
  if (t == 0) gap[bc] = (red[0] + red[1] + red[2] + red[3]) * (1.0f / HWsz);
}

// ---------------- gate: softmax + top2 + aux loss ----------------
__global__ void gate_k(const float* __restrict__ gap, const float* __restrict__ gwt,
                       const float* __restrict__ gb, int* __restrict__ gidx,
                       float* __restrict__ gwo, float* __restrict__ aux)
{
  const int t = threadIdx.x;  // 64 threads, one wave
  __shared__ float logits[NBAT][NEXP];
  __shared__ float gated[NBAT][NEXP];
  {
    const int b = t >> 2, e = t & 3;
    float s = gb[e];
    for (int c = 0; c < Cdim; c++) s += gap[b * Cdim + c] * gwt[e * Cdim + c];
    logits[b][e] = s;
  }
  __syncthreads();
  if (t < NBAT) {
    const int b = t;
    float p[NEXP];
    float mx = logits[b][0];
    for (int e = 1; e < NEXP; e++) mx = fmaxf(mx, logits[b][e]);
    float sum = 0.f;
    for (int e = 0; e < NEXP; e++) { p[e] = expf(logits[b][e] - mx); sum += p[e]; }
    for (int e = 0; e < NEXP; e++) p[e] /= sum;
    int i0 = 0;
    for (int e = 1; e < NEXP; e++) if (p[e] > p[i0]) i0 = e;   // ties -> lower idx (matches lax.top_k)
    int i1 = (i0 == 0) ? 1 : 0;
    for (int e = 0; e < NEXP; e++) if (e != i0 && p[e] > p[i1]) i1 = e;
    const float s2 = p[i0] + p[i1] + 1e-8f;
    const float w0 = p[i0] / s2, w1 = p[i1] / s2;
    gidx[2 * b] = i0; gidx[2 * b + 1] = i1;
    gwo[2 * b] = w0;  gwo[2 * b + 1] = w1;
    for (int e = 0; e < NEXP; e++)
      gated[b][e] = (e == i0) ? w0 : ((e == i1) ? w1 : 0.f);
  }
  __syncthreads();
  if (t == 0) {
    float imp[NEXP] = {0.f, 0.f, 0.f, 0.f};
    for (int b = 0; b < NBAT; b++)
      for (int e = 0; e < NEXP; e++) imp[e] += gated[b][e];
    float mean = 0.f;
    for (int e = 0; e < NEXP; e++) mean += imp[e];
    mean *= 0.25f;
    float var = 0.f;
    for (int e = 0; e < NEXP; e++) { const float d = imp[e] - mean; var += d * d; }
    var *= 0.25f;
    aux[0] = var / (mean * mean + 1e-10f);
  }
}

// ---------------- fused top-2 expert MLP ----------------
// grid (256, 16): blockIdx.x = 64-wide position tile, blockIdx.y = sample b.
// 4 waves in 2x2 (mh, nh) arrangement over (out-channel, position) tiles.
// v2: T14 issue-early register prefetch of all weight A-fragments one phase
//     ahead (plain reg loads survive barriers via counted vmcnt at use),
//     nontemporal out stores (don't evict weights from L2),
//     s_setprio(1) around MFMA clusters.
__global__ __launch_bounds__(256, 2)
void moe_main_k(const float* __restrict__ x, float* __restrict__ out,
                const _Float16* __restrict__ W1f, const _Float16* __restrict__ W2f,
                const _Float16* __restrict__ W3f,
                const float* __restrict__ b1f, const float* __restrict__ b2f,
                const float* __restrict__ b3f,
                const int* __restrict__ gidx, const float* __restrict__ gwv)
{
  __shared__ __align__(16) _Float16 Xs[64][72];   // [n][c], row 144 B (odd 16B mult -> uniform banks)
  __shared__ __align__(16) _Float16 H1[64][136];  // [n][k], row 272 B (odd 16B mult)
  __shared__ __align__(16) _Float16 H2[64][136];

  const int b  = blockIdx.y;
  const int n0 = blockIdx.x << 6;
  const int t  = threadIdx.x;
  const int w  = t >> 6;
  const int lane = t & 63;
  const int ln = lane & 15;   // MFMA n / m lane index
  const int q  = lane >> 4;   // quad
  const int mh = w >> 1;      // out-channel half
  const int nh = w & 1;       // position half

  const int   ea0 = gidx[2 * b], ea1 = gidx[2 * b + 1];
  const float wa0 = gwv[2 * b],  wa1 = gwv[2 * b + 1];

  // ---- prefetch slot-0 L1 A-fragments into regs (overlaps X staging + barrier)
  h8 A1[4][2];
  {
    const _Float16* w1 = W1f + ea0 * (HIDd * Cdim);
#pragma unroll
    for (int mi = 0; mi < 4; mi++) {
      const int m0 = (((mh << 2) + mi) << 4);
      const _Float16* p = w1 + (m0 + ln) * Cdim + q * 8;
      A1[mi][0] = *(const h8*)(p);
      A1[mi][1] = *(const h8*)(p + 32);
    }
  }

  // ---- stage X tile (64c x 64n) into Xs[n][c] as f16
  {
    const int c0 = t >> 4;              // 0..15
    const int n4 = (t & 15) << 2;       // 0,4,...,60
    const float* xb = x + (size_t)b * (Cdim * HWsz) + n0;
#pragma unroll
    for (int ci = 0; ci < 4; ci++) {
      const int c = c0 + (ci << 4);
      const float4 v = *(const float4*)(xb + (size_t)c * HWsz + n4);
      Xs[n4 + 0][c] = (_Float16)v.x;
      Xs[n4 + 1][c] = (_Float16)v.y;
      Xs[n4 + 2][c] = (_Float16)v.z;
      Xs[n4 + 3][c] = (_Float16)v.w;
    }
  }

  f4 oacc[2][2];
#pragma unroll
  for (int i = 0; i < 2; i++)
#pragma unroll
    for (int j = 0; j < 2; j++)
      oacc[i][j] = f4{0.f, 0.f, 0.f, 0.f};

  __syncthreads();

#pragma unroll 1
  for (int slot = 0; slot < 2; slot++) {
    const int   e  = slot ? ea1 : ea0;
    const int   en = slot ? ea0 : ea1;   // next slot's expert (slot1: redundant reload, harmless)
    const float we = slot ? wa1 : wa0;
    const _Float16* w2 = W2f + e * (HIDd * HIDd);
    const _Float16* w3 = W3f + e * (Cdim * HIDd);
    const float* bb1 = b1f + e * HIDd;
    const float* bb2 = b2f + e * HIDd;
    const float* bb3 = b3f + e * Cdim;

    // ---- prefetch L2 A-fragments (in flight during all of Layer 1)
    h8 A2[4][4];
#pragma unroll
    for (int mi = 0; mi < 4; mi++) {
      const int m0 = (((mh << 2) + mi) << 4);
      const _Float16* p = w2 + (m0 + ln) * HIDd + q * 8;
#pragma unroll
      for (int ks = 0; ks < 4; ks++) A2[mi][ks] = *(const h8*)(p + ks * 32);
    }

    // ---- Layer 1: H1[n][o] = relu(W1' X + b1'), K=64 (uses prefetched A1)
#pragma unroll
    for (int ni = 0; ni < 2; ni++) {
      const int nrow = ((nh << 1) + ni) * 16 + ln;
      const h8 bf0 = *(const h8*)&Xs[nrow][q * 8];
      const h8 bf1 = *(const h8*)&Xs[nrow][32 + q * 8];
      __builtin_amdgcn_s_setprio(1);
#pragma unroll
      for (int mi = 0; mi < 4; mi++) {
        const int m0 = (((mh << 2) + mi) << 4);
        f4 acc = {0.f, 0.f, 0.f, 0.f};
        acc = __builtin_amdgcn_mfma_f32_16x16x32_f16(A1[mi][0], bf0, acc, 0, 0, 0);
        acc = __builtin_amdgcn_mfma_f32_16x16x32_f16(A1[mi][1], bf1, acc, 0, 0, 0);
        const f4 bias = *(const f4*)(bb1 + m0 + q * 4);
        h4 hv;
#pragma unroll
        for (int r = 0; r < 4; r++) hv[r] = (_Float16)fmaxf(acc[r] + bias[r], 0.f);
        *(h4*)&H1[nrow][m0 + q * 4] = hv;
      }
      __builtin_amdgcn_s_setprio(0);
    }

    // ---- prefetch L3 A-fragments (in flight across barrier + Layer 2)
    h8 A3[2][4];
#pragma unroll
    for (int mi = 0; mi < 2; mi++) {
      const int m0 = (((mh << 1) + mi) << 4);
      const _Float16* p = w3 + (m0 + ln) * HIDd + q * 8;
#pragma unroll
      for (int ks = 0; ks < 4; ks++) A3[mi][ks] = *(const h8*)(p + ks * 32);
    }

    __syncthreads();

    // ---- Layer 2: H2 = relu(W2' H1 + b2'), K=128 (uses prefetched A2)
#pragma unroll
    for (int ni = 0; ni < 2; ni++) {
      const int nrow = ((nh << 1) + ni) * 16 + ln;
      h8 bf[4];
#pragma unroll
      for (int ks = 0; ks < 4; ks++) bf[ks] = *(const h8*)&H1[nrow][ks * 32 + q * 8];
      __builtin_amdgcn_s_setprio(1);
#pragma unroll
      for (int mi = 0; mi < 4; mi++) {
        const int m0 = (((mh << 2) + mi) << 4);
        f4 acc = {0.f, 0.f, 0.f, 0.f};
#pragma unroll
        for (int ks = 0; ks < 4; ks++)
          acc = __builtin_amdgcn_mfma_f32_16x16x32_f16(A2[mi][ks], bf[ks], acc, 0, 0, 0);
        const f4 bias = *(const f4*)(bb2 + m0 + q * 4);
        h4 hv;
#pragma unroll
        for (int r = 0; r < 4; r++) hv[r] = (_Float16)fmaxf(acc[r] + bias[r], 0.f);
        *(h4*)&H2[nrow][m0 + q * 4] = hv;
      }
      __builtin_amdgcn_s_setprio(0);
    }

    // ---- prefetch next slot's L1 A-fragments (in flight across barrier + Layer 3)
    {
      const _Float16* w1n = W1f + en * (HIDd * Cdim);
#pragma unroll
      for (int mi = 0; mi < 4; mi++) {
        const int m0 = (((mh << 2) + mi) << 4);
        const _Float16* p = w1n + (m0 + ln) * Cdim + q * 8;
        A1[mi][0] = *(const h8*)(p);
        A1[mi][1] = *(const h8*)(p + 32);
      }
    }

    __syncthreads();

    // ---- Layer 3: oacc += we * (W3 H2 + b3), M=64, K=128 (uses prefetched A3)
#pragma unroll
    for (int ni = 0; ni < 2; ni++) {
      const int nrow = ((nh << 1) + ni) * 16 + ln;
      h8 bf[4];
#pragma unroll
      for (int ks = 0; ks < 4; ks++) bf[ks] = *(const h8*)&H2[nrow][ks * 32 + q * 8];
      __builtin_amdgcn_s_setprio(1);
#pragma unroll
      for (int mi = 0; mi < 2; mi++) {
        const int m0 = (((mh << 1) + mi) << 4);
        f4 acc = {0.f, 0.f, 0.f, 0.f};
#pragma unroll
        for (int ks = 0; ks < 4; ks++)
          acc = __builtin_amdgcn_mfma_f32_16x16x32_f16(A3[mi][ks], bf[ks], acc, 0, 0, 0);
        const f4 bias = *(const f4*)(bb3 + m0 + q * 4);
#pragma unroll
        for (int r = 0; r < 4; r++) oacc[mi][ni][r] += we * (acc[r] + bias[r]);
      }
      __builtin_amdgcn_s_setprio(0);
    }
    // No extra barrier needed: next slot's first H1 write is ordered after the
    // post-L2 barrier (all H1 reads done); H2 writes after the post-L1 barrier.
  }

  // ---- store output (fp32, nontemporal: streaming, never re-read)
#pragma unroll
  for (int mi = 0; mi < 2; mi++)
#pragma unroll
    for (int ni = 0; ni < 2; ni++) {
      const int c = ((mh << 1) + mi) * 16 + q * 4;
      const int n = n0 + ((nh << 1) + ni) * 16 + ln;
#pragma unroll
      for (int r = 0; r < 4; r++)
        __builtin_nontemporal_store(oacc[mi][ni][r],
                                    &out[((size_t)(b * Cdim + c + r)) * HWsz + n]);
    }
}

extern "C" void kernel_launch(void* const* d_in, const int* in_sizes, int n_in,
                              void* d_out, int out_size, void* d_ws, size_t ws_size,
                              hipStream_t stream)
{
  const float* x   = (const float*)d_in[0];
  const float* W1  = (const float*)d_in[1];
  const float* b1  = (const float*)d_in[2];
  const float* g1  = (const float*)d_in[3];
  const float* be1 = (const float*)d_in[4];
  const float* m1  = (const float*)d_in[5];
  const float* v1  = (const float*)d_in[6];
  const float* W2  = (const float*)d_in[7];
  const float* b2  = (const float*)d_in[8];
  const float* g2  = (const float*)d_in[9];
  const float* be2 = (const float*)d_in[10];
  const float* m2  = (const float*)d_in[11];
  const float* v2  = (const float*)d_in[12];
  const float* W3  = (const float*)d_in[13];
  const float* b3  = (const float*)d_in[14];
  const float* gwt = (const float*)d_in[15];
  const float* gb  = (const float*)d_in[16];

  char* ws = (char*)d_ws;
  _Float16* W1f = (_Float16*)(ws + OFF_W1F);
  _Float16* W2f = (_Float16*)(ws + OFF_W2F);
  _Float16* W3f = (_Float16*)(ws + OFF_W3F);
  float* b1f = (float*)(ws + OFF_B1F);
  float* b2f = (float*)(ws + OFF_B2F);
  float* b3f = (float*)(ws + OFF_B3F);
  float* gap = (float*)(ws + OFF_GAP);
  int*   gidx = (int*)(ws + OFF_GIDX);
  float* gwo = (float*)(ws + OFF_GW);

  float* out = (float*)d_out;
  float* aux = out + (size_t)NBAT * Cdim * HWsz;  // d_out[16777216]

  hipLaunchKernelGGL(fold_k, dim3(518), dim3(256), 0, stream,
                     W1, b1, g1, be1, m1, v1, W2, b2, g2, be2, m2, v2, W3, b3,
                     W1f, W2f, W3f, b1f, b2f, b3f);
  hipLaunchKernelGGL(gap_k, dim3(NBAT * Cdim), dim3(256), 0, stream, x, gap);
  hipLaunchKernelGGL(gate_k, dim3(1), dim3(64), 0, stream, gap, gwt, gb, gidx, gwo, aux);
  hipLaunchKernelGGL(moe_main_k, dim3(HWsz / 64, NBAT), dim3(256), 0, stream,
                     x, out, W1f, W2f, W3f, b1f, b2f, b3f, gidx, gwo);
}

// Round 2
// 263.382 us; speedup vs baseline: 1.1162x; 1.1162x over previous
//
#include <hip/hip_runtime.h>
#include <hip/hip_bf16.h>

#define HWsz 16384
#define Cdim 64
#define HIDd 128
#define NEXP 4
#define NBAT 16

typedef _Float16 h8 __attribute__((ext_vector_type(8)));
typedef _Float16 h4 __attribute__((ext_vector_type(4)));
typedef float f4 __attribute__((ext_vector_type(4)));

// d_ws layout (bytes)
#define OFF_W1F 0        // 4*128*64 f16   = 65536 B
#define OFF_W2F 65536    // 4*128*128 f16  = 131072 B
#define OFF_W3F 196608   // 4*64*128 f16   = 65536 B
#define OFF_B1F 262144   // 4*128 f32      = 2048 B
#define OFF_B2F 264192   // 4*128 f32      = 2048 B
#define OFF_B3F 266240   // 4*64 f32       = 1024 B
#define OFF_GAP 267264   // 16*64 f32      = 4096 B
#define OFF_GIDX 271360  // 16*2 int       = 128 B
#define OFF_GW  271488   // 16*2 f32       = 128 B

// ---------------- fused BN-fold/f16-cast + global average pool ----------------
// blocks 0..1023: gap over x (b*64+c per block); blocks 1024..1541: weight fold.
__global__ void prep_k(const float* __restrict__ x, float* __restrict__ gap,
                       const float* __restrict__ W1, const float* __restrict__ b1,
                       const float* __restrict__ g1, const float* __restrict__ be1,
                       const float* __restrict__ m1, const float* __restrict__ v1,
                       const float* __restrict__ W2, const float* __restrict__ b2,
                       const float* __restrict__ g2, const float* __restrict__ be2,
                       const float* __restrict__ m2, const float* __restrict__ v2,
                       const float* __restrict__ W3, const float* __restrict__ b3,
                       _Float16* __restrict__ W1f, _Float16* __restrict__ W2f,
                       _Float16* __restrict__ W3f,
                       float* __restrict__ b1f, float* __restrict__ b2f,
                       float* __restrict__ b3f)
{
  const int t = threadIdx.x;             // 256
  if (blockIdx.x < 1024) {
    // ---- global average pool over one (b,c) row
    const int bc = blockIdx.x;
    const float* p = x + (size_t)bc * HWsz;
    float s = 0.f;
    for (int i = t; i < HWsz / 4; i += 256) {
      const float4 v = ((const float4*)p)[i];
      s += v.x + v.y + v.z + v.w;
    }
    for (int off = 32; off; off >>= 1) s += __shfl_down(s, off, 64);
    __shared__ float red[4];
    if ((t & 63) == 0) red[t >> 6] = s;
    __syncthreads();
    if (t == 0) gap[bc] = (red[0] + red[1] + red[2] + red[3]) * (1.0f / HWsz);
  } else {
    // ---- BN fold + f16 cast
    const int i = (blockIdx.x - 1024) * 256 + t;
    if (i < 32768) {                       // W1 [e][o][c], eo = i/64
      const int eo = i >> 6;
      const float inv = g1[eo] * rsqrtf(v1[eo] + 1e-5f);
      W1f[i] = (_Float16)(W1[i] * inv);
    } else if (i < 98304) {                // W2 [e][o][i], eo = j/128
      const int j = i - 32768;
      const int eo = j >> 7;
      const float inv = g2[eo] * rsqrtf(v2[eo] + 1e-5f);
      W2f[j] = (_Float16)(W2[j] * inv);
    } else if (i < 131072) {               // W3 (no BN)
      const int k = i - 98304;
      W3f[k] = (_Float16)W3[k];
    } else if (i < 131584) {               // b1'
      const int l = i - 131072;
      const float inv = g1[l] * rsqrtf(v1[l] + 1e-5f);
      b1f[l] = b1[l] * inv + be1[l] - m1[l] * inv;
    } else if (i < 132096) {               // b2'
      const int l = i - 131584;
      const float inv = g2[l] * rsqrtf(v2[l] + 1e-5f);
      b2f[l] = b2[l] * inv + be2[l] - m2[l] * inv;
    } else if (i < 132352) {               // b3'
      b3f[i - 132096] = b3[i - 132096];
    }
  }
}

// ---------------- gate: softmax + top2 + aux loss ----------------
__global__ void gate_k(const float* __restrict__ gap, const float* __restrict__ gwt,
                       const float* __restrict__ gb, int* __restrict__ gidx,
                       float* __restrict__ gwo, float* __restrict__ aux)
{
  const int t = threadIdx.x;  // 64 threads, one wave
  __shared__ float logits[NBAT][NEXP];
  __shared__ float gated[NBAT][NEXP];
  {
    const int b = t >> 2, e = t & 3;
    float s = gb[e];
    for (int c = 0; c < Cdim; c++) s += gap[b * Cdim + c] * gwt[e * Cdim + c];
    logits[b][e] = s;
  }
  __syncthreads();
  if (t < NBAT) {
    const int b = t;
    float p[NEXP];
    float mx = logits[b][0];
    for (int e = 1; e < NEXP; e++) mx = fmaxf(mx, logits[b][e]);
    float sum = 0.f;
    for (int e = 0; e < NEXP; e++) { p[e] = expf(logits[b][e] - mx); sum += p[e]; }
    for (int e = 0; e < NEXP; e++) p[e] /= sum;
    int i0 = 0;
    for (int e = 1; e < NEXP; e++) if (p[e] > p[i0]) i0 = e;   // ties -> lower idx (matches lax.top_k)
    int i1 = (i0 == 0) ? 1 : 0;
    for (int e = 0; e < NEXP; e++) if (e != i0 && p[e] > p[i1]) i1 = e;
    const float s2 = p[i0] + p[i1] + 1e-8f;
    const float w0 = p[i0] / s2, w1 = p[i1] / s2;
    gidx[2 * b] = i0; gidx[2 * b + 1] = i1;
    gwo[2 * b] = w0;  gwo[2 * b + 1] = w1;
    for (int e = 0; e < NEXP; e++)
      gated[b][e] = (e == i0) ? w0 : ((e == i1) ? w1 : 0.f);
  }
  __syncthreads();
  if (t == 0) {
    float imp[NEXP] = {0.f, 0.f, 0.f, 0.f};
    for (int b = 0; b < NBAT; b++)
      for (int e = 0; e < NEXP; e++) imp[e] += gated[b][e];
    float mean = 0.f;
    for (int e = 0; e < NEXP; e++) mean += imp[e];
    mean *= 0.25f;
    float var = 0.f;
    for (int e = 0; e < NEXP; e++) { const float d = imp[e] - mean; var += d * d; }
    var *= 0.25f;
    aux[0] = var / (mean * mean + 1e-10f);
  }
}

// ---------------- fused top-2 expert MLP ----------------
// v3: grid (2048): blockIdx.x -> (sample b, 128-position pair of 64-tiles).
// Slot-outer loop: per expert slot, load this wave's FULL A-fragment set
// (A1:8 + A2:16 + A3:8 h8 = 128 VGPRs) ONCE, stage BOTH X tiles, then run
// both tiles through L1->L2->L3 with weights register-resident. Barrier
// phases contain only LDS + MFMA work (no global latency inside phases).
// oacc[2] kept in regs across slots -> single write, no RMW.
__global__ __launch_bounds__(256, 2)
void moe_main_k(const float* __restrict__ x, float* __restrict__ out,
                const _Float16* __restrict__ W1f, const _Float16* __restrict__ W2f,
                const _Float16* __restrict__ W3f,
                const float* __restrict__ b1f, const float* __restrict__ b2f,
                const float* __restrict__ b3f,
                const int* __restrict__ gidx, const float* __restrict__ gwv)
{
  __shared__ __align__(16) _Float16 Xs[2][64][72];  // [tile][n][c], row 144 B
  __shared__ __align__(16) _Float16 H1[64][136];    // [n][k], row 272 B
  __shared__ __align__(16) _Float16 H2[64][136];

  const int bx = blockIdx.x;
  const int b  = bx >> 7;            // sample
  const int n0 = (bx & 127) << 7;    // 128-position base
  const int t  = threadIdx.x;
  const int w  = t >> 6;
  const int lane = t & 63;
  const int ln = lane & 15;   // MFMA n / m lane index
  const int q  = lane >> 4;   // quad
  const int mh = w >> 1;      // out-channel half
  const int nh = w & 1;       // position half

  const int   ea0 = gidx[2 * b], ea1 = gidx[2 * b + 1];
  const float wa0 = gwv[2 * b],  wa1 = gwv[2 * b + 1];

  f4 oacc[2][2][2];   // [tile][mi][ni]
#pragma unroll
  for (int tt = 0; tt < 2; tt++)
#pragma unroll
    for (int i = 0; i < 2; i++)
#pragma unroll
      for (int j = 0; j < 2; j++)
        oacc[tt][i][j] = f4{0.f, 0.f, 0.f, 0.f};

#pragma unroll 1
  for (int slot = 0; slot < 2; slot++) {
    const int   e  = slot ? ea1 : ea0;
    const float we = slot ? wa1 : wa0;
    const _Float16* w1 = W1f + e * (HIDd * Cdim);
    const _Float16* w2 = W2f + e * (HIDd * HIDd);
    const _Float16* w3 = W3f + e * (Cdim * HIDd);
    const float* bb1 = b1f + e * HIDd;
    const float* bb2 = b2f + e * HIDd;
    const float* bb3 = b3f + e * Cdim;

    // ---- stage BOTH X tiles (issue HBM loads first)
    {
      const int c0 = t >> 4;              // 0..15
      const int n4 = (t & 15) << 2;       // 0,4,...,60
      const float* xb = x + (size_t)b * (Cdim * HWsz) + n0;
#pragma unroll
      for (int tt = 0; tt < 2; tt++)
#pragma unroll
        for (int ci = 0; ci < 4; ci++) {
          const int c = c0 + (ci << 4);
          const float4 v = *(const float4*)(xb + (size_t)c * HWsz + (tt << 6) + n4);
          Xs[tt][n4 + 0][c] = (_Float16)v.x;
          Xs[tt][n4 + 1][c] = (_Float16)v.y;
          Xs[tt][n4 + 2][c] = (_Float16)v.z;
          Xs[tt][n4 + 3][c] = (_Float16)v.w;
        }
    }

    // ---- load this wave's full weight fragment set (register-resident)
    h8 A1[4][2], A2[4][4], A3[2][4];
#pragma unroll
    for (int mi = 0; mi < 4; mi++) {
      const int m0 = (((mh << 2) + mi) << 4);
      const _Float16* p1 = w1 + (m0 + ln) * Cdim + q * 8;
      A1[mi][0] = *(const h8*)(p1);
      A1[mi][1] = *(const h8*)(p1 + 32);
      const _Float16* p2 = w2 + (m0 + ln) * HIDd + q * 8;
#pragma unroll
      for (int ks = 0; ks < 4; ks++) A2[mi][ks] = *(const h8*)(p2 + ks * 32);
    }
#pragma unroll
    for (int mi = 0; mi < 2; mi++) {
      const int m0 = (((mh << 1) + mi) << 4);
      const _Float16* p3 = w3 + (m0 + ln) * HIDd + q * 8;
#pragma unroll
      for (int ks = 0; ks < 4; ks++) A3[mi][ks] = *(const h8*)(p3 + ks * 32);
    }

    __syncthreads();   // X tiles staged

#pragma unroll
    for (int tl = 0; tl < 2; tl++) {
      // ---- Layer 1: H1[n][o] = relu(W1' X + b1'), K=64
#pragma unroll
      for (int ni = 0; ni < 2; ni++) {
        const int nrow = ((nh << 1) + ni) * 16 + ln;
        const h8 bf0 = *(const h8*)&Xs[tl][nrow][q * 8];
        const h8 bf1 = *(const h8*)&Xs[tl][nrow][32 + q * 8];
        __builtin_amdgcn_s_setprio(1);
#pragma unroll
        for (int mi = 0; mi < 4; mi++) {
          const int m0 = (((mh << 2) + mi) << 4);
          f4 acc = {0.f, 0.f, 0.f, 0.f};
          acc = __builtin_amdgcn_mfma_f32_16x16x32_f16(A1[mi][0], bf0, acc, 0, 0, 0);
          acc = __builtin_amdgcn_mfma_f32_16x16x32_f16(A1[mi][1], bf1, acc, 0, 0, 0);
          const f4 bias = *(const f4*)(bb1 + m0 + q * 4);
          h4 hv;
#pragma unroll
          for (int r = 0; r < 4; r++) hv[r] = (_Float16)fmaxf(acc[r] + bias[r], 0.f);
          *(h4*)&H1[nrow][m0 + q * 4] = hv;
        }
        __builtin_amdgcn_s_setprio(0);
      }
      __syncthreads();   // H1 ready (and Xs[tl] reads done)

      // ---- Layer 2: H2 = relu(W2' H1 + b2'), K=128
#pragma unroll
      for (int ni = 0; ni < 2; ni++) {
        const int nrow = ((nh << 1) + ni) * 16 + ln;
        h8 bf[4];
#pragma unroll
        for (int ks = 0; ks < 4; ks++) bf[ks] = *(const h8*)&H1[nrow][ks * 32 + q * 8];
        __builtin_amdgcn_s_setprio(1);
#pragma unroll
        for (int mi = 0; mi < 4; mi++) {
          const int m0 = (((mh << 2) + mi) << 4);
          f4 acc = {0.f, 0.f, 0.f, 0.f};
#pragma unroll
          for (int ks = 0; ks < 4; ks++)
            acc = __builtin_amdgcn_mfma_f32_16x16x32_f16(A2[mi][ks], bf[ks], acc, 0, 0, 0);
          const f4 bias = *(const f4*)(bb2 + m0 + q * 4);
          h4 hv;
#pragma unroll
          for (int r = 0; r < 4; r++) hv[r] = (_Float16)fmaxf(acc[r] + bias[r], 0.f);
          *(h4*)&H2[nrow][m0 + q * 4] = hv;
        }
        __builtin_amdgcn_s_setprio(0);
      }
      __syncthreads();   // H2 ready (and H1 reads done -> next tile's L1 may write H1)

      // ---- Layer 3: oacc[tl] += we * (W3 H2 + b3), M=64, K=128
#pragma unroll
      for (int ni = 0; ni < 2; ni++) {
        const int nrow = ((nh << 1) + ni) * 16 + ln;
        h8 bf[4];
#pragma unroll
        for (int ks = 0; ks < 4; ks++) bf[ks] = *(const h8*)&H2[nrow][ks * 32 + q * 8];
        __builtin_amdgcn_s_setprio(1);
#pragma unroll
        for (int mi = 0; mi < 2; mi++) {
          const int m0 = (((mh << 1) + mi) << 4);
          f4 acc = {0.f, 0.f, 0.f, 0.f};
#pragma unroll
          for (int ks = 0; ks < 4; ks++)
            acc = __builtin_amdgcn_mfma_f32_16x16x32_f16(A3[mi][ks], bf[ks], acc, 0, 0, 0);
          const f4 bias = *(const f4*)(bb3 + m0 + q * 4);
#pragma unroll
          for (int r = 0; r < 4; r++) oacc[tl][mi][ni][r] += we * (acc[r] + bias[r]);
        }
        __builtin_amdgcn_s_setprio(0);
      }
      // t1's L1 (writes H1) is safe: H1 readers finished at post-L2 barrier.
      // t1's L2 (writes H2) is safe: separated from t0's L3 (H2 reads) by the
      // post-L1(t1) barrier.
    }
    // Next slot's X staging is safe: all waves passed the post-L2(t1) barrier,
    // which is after every Xs read (L1(t1)).
  }

  // ---- store output (fp32, nontemporal: streaming, never re-read)
#pragma unroll
  for (int tl = 0; tl < 2; tl++)
#pragma unroll
    for (int mi = 0; mi < 2; mi++)
#pragma unroll
      for (int ni = 0; ni < 2; ni++) {
        const int c = ((mh << 1) + mi) * 16 + q * 4;
        const int n = n0 + (tl << 6) + ((nh << 1) + ni) * 16 + ln;
#pragma unroll
        for (int r = 0; r < 4; r++)
          __builtin_nontemporal_store(oacc[tl][mi][ni][r],
                                      &out[((size_t)(b * Cdim + c + r)) * HWsz + n]);
      }
}

extern "C" void kernel_launch(void* const* d_in, const int* in_sizes, int n_in,
                              void* d_out, int out_size, void* d_ws, size_t ws_size,
                              hipStream_t stream)
{
  const float* x   = (const float*)d_in[0];
  const float* W1  = (const float*)d_in[1];
  const float* b1  = (const float*)d_in[2];
  const float* g1  = (const float*)d_in[3];
  const float* be1 = (const float*)d_in[4];
  const float* m1  = (const float*)d_in[5];
  const float* v1  = (const float*)d_in[6];
  const float* W2  = (const float*)d_in[7];
  const float* b2  = (const float*)d_in[8];
  const float* g2  = (const float*)d_in[9];
  const float* be2 = (const float*)d_in[10];
  const float* m2  = (const float*)d_in[11];
  const float* v2  = (const float*)d_in[12];
  const float* W3  = (const float*)d_in[13];
  const float* b3  = (const float*)d_in[14];
  const float* gwt = (const float*)d_in[15];
  const float* gb  = (const float*)d_in[16];

  char* ws = (char*)d_ws;
  _Float16* W1f = (_Float16*)(ws + OFF_W1F);
  _Float16* W2f = (_Float16*)(ws + OFF_W2F);
  _Float16* W3f = (_Float16*)(ws + OFF_W3F);
  float* b1f = (float*)(ws + OFF_B1F);
  float* b2f = (float*)(ws + OFF_B2F);
  float* b3f = (float*)(ws + OFF_B3F);
  float* gap = (float*)(ws + OFF_GAP);
  int*   gidx = (int*)(ws + OFF_GIDX);
  float* gwo = (float*)(ws + OFF_GW);

  float* out = (float*)d_out;
  float* aux = out + (size_t)NBAT * Cdim * HWsz;  // d_out[16777216]

  hipLaunchKernelGGL(prep_k, dim3(1542), dim3(256), 0, stream,
                     x, gap, W1, b1, g1, be1, m1, v1, W2, b2, g2, be2, m2, v2,
                     W3, b3, W1f, W2f, W3f, b1f, b2f, b3f);
  hipLaunchKernelGGL(gate_k, dim3(1), dim3(64), 0, stream, gap, gwt, gb, gidx, gwo, aux);
  hipLaunchKernelGGL(moe_main_k, dim3(2048), dim3(256), 0, stream,
                     x, out, W1f, W2f, W3f, b1f, b2f, b3f, gidx, gwo);
}

// Round 4
// 223.759 us; speedup vs baseline: 1.3138x; 1.1771x over previous
//
#include <hip/hip_runtime.h>
#include <hip/hip_bf16.h>

#define HWsz 16384
#define Cdim 64
#define HIDd 128
#define NEXP 4
#define NBAT 16

typedef _Float16 h8 __attribute__((ext_vector_type(8)));
typedef _Float16 h4 __attribute__((ext_vector_type(4)));
typedef float f4 __attribute__((ext_vector_type(4)));

// d_ws layout (bytes)
#define OFF_W1F 0        // 4*128*64 f16   = 65536 B
#define OFF_W2F 65536    // 4*128*128 f16  = 131072 B
#define OFF_W3F 196608   // 4*64*128 f16   = 65536 B
#define OFF_B1F 262144   // 4*128 f32      = 2048 B
#define OFF_B2F 264192   // 4*128 f32      = 2048 B
#define OFF_B3F 266240   // 4*64 f32       = 1024 B
#define OFF_GAP 267264   // 16*64 f32      = 4096 B
#define OFF_GIDX 271360  // 16*2 int       = 128 B
#define OFF_GW  271488   // 16*2 f32       = 128 B

// pin a 16B fragment in VGPRs: forbids the compiler from sinking/rematerializing
// the load that produced it (R1/R2 lesson: plain loads get sunk to uses).
__device__ __forceinline__ void pinv(f4& v) { asm volatile("" : "+v"(v)); }

// ---------------- fused BN-fold/f16-cast + global average pool ----------------
// blocks 0..1023: gap over x (b*64+c per block); blocks 1024..1541: weight fold.
__global__ void prep_k(const float* __restrict__ x, float* __restrict__ gap,
                       const float* __restrict__ W1, const float* __restrict__ b1,
                       const float* __restrict__ g1, const float* __restrict__ be1,
                       const float* __restrict__ m1, const float* __restrict__ v1,
                       const float* __restrict__ W2, const float* __restrict__ b2,
                       const float* __restrict__ g2, const float* __restrict__ be2,
                       const float* __restrict__ m2, const float* __restrict__ v2,
                       const float* __restrict__ W3, const float* __restrict__ b3,
                       _Float16* __restrict__ W1f, _Float16* __restrict__ W2f,
                       _Float16* __restrict__ W3f,
                       float* __restrict__ b1f, float* __restrict__ b2f,
                       float* __restrict__ b3f)
{
  const int t = threadIdx.x;             // 256
  if (blockIdx.x < 1024) {
    const int bc = blockIdx.x;
    const float* p = x + (size_t)bc * HWsz;
    float s = 0.f;
    for (int i = t; i < HWsz / 4; i += 256) {
      const float4 v = ((const float4*)p)[i];
      s += v.x + v.y + v.z + v.w;
    }
    for (int off = 32; off; off >>= 1) s += __shfl_down(s, off, 64);
    __shared__ float red[4];
    if ((t & 63) == 0) red[t >> 6] = s;
    __syncthreads();
    if (t == 0) gap[bc] = (red[0] + red[1] + red[2] + red[3]) * (1.0f / HWsz);
  } else {
    const int i = (blockIdx.x - 1024) * 256 + t;
    if (i < 32768) {                       // W1 [e][o][c], eo = i/64
      const int eo = i >> 6;
      const float inv = g1[eo] * rsqrtf(v1[eo] + 1e-5f);
      W1f[i] = (_Float16)(W1[i] * inv);
    } else if (i < 98304) {                // W2 [e][o][i], eo = j/128
      const int j = i - 32768;
      const int eo = j >> 7;
      const float inv = g2[eo] * rsqrtf(v2[eo] + 1e-5f);
      W2f[j] = (_Float16)(W2[j] * inv);
    } else if (i < 131072) {               // W3 (no BN)
      const int k = i - 98304;
      W3f[k] = (_Float16)W3[k];
    } else if (i < 131584) {               // b1'
      const int l = i - 131072;
      const float inv = g1[l] * rsqrtf(v1[l] + 1e-5f);
      b1f[l] = b1[l] * inv + be1[l] - m1[l] * inv;
    } else if (i < 132096) {               // b2'
      const int l = i - 131584;
      const float inv = g2[l] * rsqrtf(v2[l] + 1e-5f);
      b2f[l] = b2[l] * inv + be2[l] - m2[l] * inv;
    } else if (i < 132352) {               // b3'
      b3f[i - 132096] = b3[i - 132096];
    }
  }
}

// ---------------- gate: softmax + top2 + aux loss ----------------
__global__ void gate_k(const float* __restrict__ gap, const float* __restrict__ gwt,
                       const float* __restrict__ gb, int* __restrict__ gidx,
                       float* __restrict__ gwo, float* __restrict__ aux)
{
  const int t = threadIdx.x;  // 64 threads, one wave
  __shared__ float logits[NBAT][NEXP];
  __shared__ float gated[NBAT][NEXP];
  {
    const int b = t >> 2, e = t & 3;
    float s = gb[e];
    for (int c = 0; c < Cdim; c++) s += gap[b * Cdim + c] * gwt[e * Cdim + c];
    logits[b][e] = s;
  }
  __syncthreads();
  if (t < NBAT) {
    const int b = t;
    float p[NEXP];
    float mx = logits[b][0];
    for (int e = 1; e < NEXP; e++) mx = fmaxf(mx, logits[b][e]);
    float sum = 0.f;
    for (int e = 0; e < NEXP; e++) { p[e] = expf(logits[b][e] - mx); sum += p[e]; }
    for (int e = 0; e < NEXP; e++) p[e] /= sum;
    int i0 = 0;
    for (int e = 1; e < NEXP; e++) if (p[e] > p[i0]) i0 = e;   // ties -> lower idx (matches lax.top_k)
    int i1 = (i0 == 0) ? 1 : 0;
    for (int e = 0; e < NEXP; e++) if (e != i0 && p[e] > p[i1]) i1 = e;
    const float s2 = p[i0] + p[i1] + 1e-8f;
    const float w0 = p[i0] / s2, w1 = p[i1] / s2;
    gidx[2 * b] = i0; gidx[2 * b + 1] = i1;
    gwo[2 * b] = w0;  gwo[2 * b + 1] = w1;
    for (int e = 0; e < NEXP; e++)
      gated[b][e] = (e == i0) ? w0 : ((e == i1) ? w1 : 0.f);
  }
  __syncthreads();
  if (t == 0) {
    float imp[NEXP] = {0.f, 0.f, 0.f, 0.f};
    for (int b = 0; b < NBAT; b++)
      for (int e = 0; e < NEXP; e++) imp[e] += gated[b][e];
    float mean = 0.f;
    for (int e = 0; e < NEXP; e++) mean += imp[e];
    mean *= 0.25f;
    float var = 0.f;
    for (int e = 0; e < NEXP; e++) { const float d = imp[e] - mean; var += d * d; }
    var *= 0.25f;
    aux[0] = var / (mean * mean + 1e-10f);
  }
}

// ---------------- fused top-2 expert MLP ----------------
// v4 (resubmit; R3 was an infra flake — container failed before measuring):
// grid (2048): blockIdx.x -> (sample b, 128-position pair of 64-tiles).
//  - X staged ONCE per block (slot-invariant; v3 staged it twice).
//  - Weight fragments loaded per slot as f4 and PINNED via inline asm so the
//    compiler cannot sink the loads into the MFMA phases (VGPR must be ~230).
//  - Biases staged to LDS (saves ~40 VGPRs vs register-resident).
//  - H1 double-buffered; phases merged: L1t0 | L2t0+L1t1 | L3t0 | L2t1 | L3t1
//    -> the fat middle phase has 48 independent MFMA chains for ILP.
__global__ __launch_bounds__(256, 2)
void moe_main_k(const float* __restrict__ x, float* __restrict__ out,
                const _Float16* __restrict__ W1f, const _Float16* __restrict__ W2f,
                const _Float16* __restrict__ W3f,
                const float* __restrict__ b1f, const float* __restrict__ b2f,
                const float* __restrict__ b3f,
                const int* __restrict__ gidx, const float* __restrict__ gwv)
{
  __shared__ __align__(16) _Float16 Xs[2][64][72];   // [tile][n][c], row 144 B
  __shared__ __align__(16) _Float16 H1[2][64][136];  // [buf][n][k], row 272 B
  __shared__ __align__(16) _Float16 H2[64][136];
  __shared__ __align__(16) float    bias_lds[2][320]; // [slot][b1:0-127|b2:128-255|b3:256-319]

  const int bx = blockIdx.x;
  const int b  = bx >> 7;            // sample
  const int n0 = (bx & 127) << 7;    // 128-position base
  const int t  = threadIdx.x;
  const int w  = t >> 6;
  const int lane = t & 63;
  const int ln = lane & 15;   // MFMA n / m lane index
  const int q  = lane >> 4;   // quad
  const int mh = w >> 1;      // out-channel half
  const int nh = w & 1;       // position half

  const int   ea0 = gidx[2 * b], ea1 = gidx[2 * b + 1];
  const float wa0 = gwv[2 * b],  wa1 = gwv[2 * b + 1];

  // ---- stage biases for both slots into LDS
  for (int i = t; i < 640; i += 256) {
    const int sl = i >= 320;
    const int j  = i - (sl ? 320 : 0);
    const int e  = sl ? ea1 : ea0;
    float v;
    if (j < 128)      v = b1f[e * HIDd + j];
    else if (j < 256) v = b2f[e * HIDd + (j - 128)];
    else              v = b3f[e * Cdim + (j - 256)];
    bias_lds[sl][j] = v;
  }

  // ---- stage BOTH X tiles, once per block (slot-invariant)
  {
    const int c0 = t >> 4;              // 0..15
    const int n4 = (t & 15) << 2;       // 0,4,...,60
    const float* xb = x + (size_t)b * (Cdim * HWsz) + n0;
#pragma unroll
    for (int tt = 0; tt < 2; tt++)
#pragma unroll
      for (int ci = 0; ci < 4; ci++) {
        const int c = c0 + (ci << 4);
        const float4 v = *(const float4*)(xb + (size_t)c * HWsz + (tt << 6) + n4);
        Xs[tt][n4 + 0][c] = (_Float16)v.x;
        Xs[tt][n4 + 1][c] = (_Float16)v.y;
        Xs[tt][n4 + 2][c] = (_Float16)v.z;
        Xs[tt][n4 + 3][c] = (_Float16)v.w;
      }
  }

  f4 oacc[2][2][2];   // [tile][mi][ni]
#pragma unroll
  for (int tt = 0; tt < 2; tt++)
#pragma unroll
    for (int i = 0; i < 2; i++)
#pragma unroll
      for (int j = 0; j < 2; j++)
        oacc[tt][i][j] = f4{0.f, 0.f, 0.f, 0.f};

  __syncthreads();   // X + biases staged

#pragma unroll 1
  for (int slot = 0; slot < 2; slot++) {
    const int   e  = slot ? ea1 : ea0;
    const float we = slot ? wa1 : wa0;
    const _Float16* w1 = W1f + e * (HIDd * Cdim);
    const _Float16* w2 = W2f + e * (HIDd * HIDd);
    const _Float16* w3 = W3f + e * (Cdim * HIDd);

    // ---- load this wave's full weight fragment set, then PIN (batched waits)
    f4 A1[4][2], A2[4][4], A3[2][4];
#pragma unroll
    for (int mi = 0; mi < 4; mi++) {
      const int m0 = (((mh << 2) + mi) << 4);
      const _Float16* p1 = w1 + (m0 + ln) * Cdim + q * 8;
      A1[mi][0] = *(const f4*)(p1);
      A1[mi][1] = *(const f4*)(p1 + 32);
      const _Float16* p2 = w2 + (m0 + ln) * HIDd + q * 8;
#pragma unroll
      for (int ks = 0; ks < 4; ks++) A2[mi][ks] = *(const f4*)(p2 + ks * 32);
    }
#pragma unroll
    for (int mi = 0; mi < 2; mi++) {
      const int m0 = (((mh << 1) + mi) << 4);
      const _Float16* p3 = w3 + (m0 + ln) * HIDd + q * 8;
#pragma unroll
      for (int ks = 0; ks < 4; ks++) A3[mi][ks] = *(const f4*)(p3 + ks * 32);
    }
#pragma unroll
    for (int mi = 0; mi < 4; mi++) {
      pinv(A1[mi][0]); pinv(A1[mi][1]);
#pragma unroll
      for (int ks = 0; ks < 4; ks++) pinv(A2[mi][ks]);
    }
#pragma unroll
    for (int mi = 0; mi < 2; mi++)
#pragma unroll
      for (int ks = 0; ks < 4; ks++) pinv(A3[mi][ks]);

    // ---- layer bodies ----
    auto L1 = [&](int tb) {
#pragma unroll
      for (int ni = 0; ni < 2; ni++) {
        const int nrow = ((nh << 1) + ni) * 16 + ln;
        const h8 bf0 = *(const h8*)&Xs[tb][nrow][q * 8];
        const h8 bf1 = *(const h8*)&Xs[tb][nrow][32 + q * 8];
        __builtin_amdgcn_s_setprio(1);
#pragma unroll
        for (int mi = 0; mi < 4; mi++) {
          const int m0 = (((mh << 2) + mi) << 4);
          f4 acc = {0.f, 0.f, 0.f, 0.f};
          acc = __builtin_amdgcn_mfma_f32_16x16x32_f16(__builtin_bit_cast(h8, A1[mi][0]), bf0, acc, 0, 0, 0);
          acc = __builtin_amdgcn_mfma_f32_16x16x32_f16(__builtin_bit_cast(h8, A1[mi][1]), bf1, acc, 0, 0, 0);
          const f4 bias = *(const f4*)&bias_lds[slot][m0 + q * 4];
          h4 hv;
#pragma unroll
          for (int r = 0; r < 4; r++) hv[r] = (_Float16)fmaxf(acc[r] + bias[r], 0.f);
          *(h4*)&H1[tb][nrow][m0 + q * 4] = hv;
        }
        __builtin_amdgcn_s_setprio(0);
      }
    };
    auto L2 = [&](int tb) {
#pragma unroll
      for (int ni = 0; ni < 2; ni++) {
        const int nrow = ((nh << 1) + ni) * 16 + ln;
        h8 bf[4];
#pragma unroll
        for (int ks = 0; ks < 4; ks++) bf[ks] = *(const h8*)&H1[tb][nrow][ks * 32 + q * 8];
        __builtin_amdgcn_s_setprio(1);
#pragma unroll
        for (int mi = 0; mi < 4; mi++) {
          const int m0 = (((mh << 2) + mi) << 4);
          f4 acc = {0.f, 0.f, 0.f, 0.f};
#pragma unroll
          for (int ks = 0; ks < 4; ks++)
            acc = __builtin_amdgcn_mfma_f32_16x16x32_f16(__builtin_bit_cast(h8, A2[mi][ks]), bf[ks], acc, 0, 0, 0);
          const f4 bias = *(const f4*)&bias_lds[slot][128 + m0 + q * 4];
          h4 hv;
#pragma unroll
          for (int r = 0; r < 4; r++) hv[r] = (_Float16)fmaxf(acc[r] + bias[r], 0.f);
          *(h4*)&H2[nrow][m0 + q * 4] = hv;
        }
        __builtin_amdgcn_s_setprio(0);
      }
    };
    auto L3 = [&](int tb) {
#pragma unroll
      for (int ni = 0; ni < 2; ni++) {
        const int nrow = ((nh << 1) + ni) * 16 + ln;
        h8 bf[4];
#pragma unroll
        for (int ks = 0; ks < 4; ks++) bf[ks] = *(const h8*)&H2[nrow][ks * 32 + q * 8];
        __builtin_amdgcn_s_setprio(1);
#pragma unroll
        for (int mi = 0; mi < 2; mi++) {
          const int m0 = (((mh << 1) + mi) << 4);
          f4 acc = {0.f, 0.f, 0.f, 0.f};
#pragma unroll
          for (int ks = 0; ks < 4; ks++)
            acc = __builtin_amdgcn_mfma_f32_16x16x32_f16(__builtin_bit_cast(h8, A3[mi][ks]), bf[ks], acc, 0, 0, 0);
          const f4 bias = *(const f4*)&bias_lds[slot][256 + m0 + q * 4];
#pragma unroll
          for (int r = 0; r < 4; r++) oacc[tb][mi][ni][r] += we * (acc[r] + bias[r]);
        }
        __builtin_amdgcn_s_setprio(0);
      }
    };

    // ---- pipelined phase schedule (H1 double-buffered, H2 single)
    L1(0);                 // P1: X[0] -> H1[0]
    __syncthreads();
    L2(0); L1(1);          // P2 (fat): H1[0]->H2  ||  X[1]->H1[1]
    __syncthreads();
    L3(0);                 // P3: H2 -> oacc[0]
    __syncthreads();       // WAR: next phase rewrites H2
    L2(1);                 // P4: H1[1] -> H2
    __syncthreads();
    L3(1);                 // P5: H2 -> oacc[1]
    // slot boundary: next slot's H1[0] write is safe (last H1[0] read was P2,
    // barriers since); next slot's H2 write (its P2) is ordered after its own
    // post-P1 barrier, which follows this P5's H2 reads. No barrier needed.
  }

  // ---- store output (fp32, nontemporal: streaming, never re-read)
#pragma unroll
  for (int tl = 0; tl < 2; tl++)
#pragma unroll
    for (int mi = 0; mi < 2; mi++)
#pragma unroll
      for (int ni = 0; ni < 2; ni++) {
        const int c = ((mh << 1) + mi) * 16 + q * 4;
        const int n = n0 + (tl << 6) + ((nh << 1) + ni) * 16 + ln;
#pragma unroll
        for (int r = 0; r < 4; r++)
          __builtin_nontemporal_store(oacc[tl][mi][ni][r],
                                      &out[((size_t)(b * Cdim + c + r)) * HWsz + n]);
      }
}

extern "C" void kernel_launch(void* const* d_in, const int* in_sizes, int n_in,
                              void* d_out, int out_size, void* d_ws, size_t ws_size,
                              hipStream_t stream)
{
  const float* x   = (const float*)d_in[0];
  const float* W1  = (const float*)d_in[1];
  const float* b1  = (const float*)d_in[2];
  const float* g1  = (const float*)d_in[3];
  const float* be1 = (const float*)d_in[4];
  const float* m1  = (const float*)d_in[5];
  const float* v1  = (const float*)d_in[6];
  const float* W2  = (const float*)d_in[7];
  const float* b2  = (const float*)d_in[8];
  const float* g2  = (const float*)d_in[9];
  const float* be2 = (const float*)d_in[10];
  const float* m2  = (const float*)d_in[11];
  const float* v2  = (const float*)d_in[12];
  const float* W3  = (const float*)d_in[13];
  const float* b3  = (const float*)d_in[14];
  const float* gwt = (const float*)d_in[15];
  const float* gb  = (const float*)d_in[16];

  char* ws = (char*)d_ws;
  _Float16* W1f = (_Float16*)(ws + OFF_W1F);
  _Float16* W2f = (_Float16*)(ws + OFF_W2F);
  _Float16* W3f = (_Float16*)(ws + OFF_W3F);
  float* b1f = (float*)(ws + OFF_B1F);
  float* b2f = (float*)(ws + OFF_B2F);
  float* b3f = (float*)(ws + OFF_B3F);
  float* gap = (float*)(ws + OFF_GAP);
  int*   gidx = (int*)(ws + OFF_GIDX);
  float* gwo = (float*)(ws + OFF_GW);

  float* out = (float*)d_out;
  float* aux = out + (size_t)NBAT * Cdim * HWsz;  // d_out[16777216]

  hipLaunchKernelGGL(prep_k, dim3(1542), dim3(256), 0, stream,
                     x, gap, W1, b1, g1, be1, m1, v1, W2, b2, g2, be2, m2, v2,
                     W3, b3, W1f, W2f, W3f, b1f, b2f, b3f);
  hipLaunchKernelGGL(gate_k, dim3(1), dim3(64), 0, stream, gap, gwt, gb, gidx, gwo, aux);
  hipLaunchKernelGGL(moe_main_k, dim3(2048), dim3(256), 0, stream,
                     x, out, W1f, W2f, W3f, b1f, b2f, b3f, gidx, gwo);
}